// Round 8
// baseline (203.525 us; speedup 1.0000x reference)
//
#include <hip/hip_runtime.h>
#include <hip/hip_cooperative_groups.h>

namespace cg = cooperative_groups;

// YOLO NMS post-processing, exact reimplementation of the JAX reference.
//  * valid = obj >= 0.8 -> ~2130 valid/image << TOPK=4096: top_k never drops
//    a valid det; invalid dets can neither suppress nor be kept.
//  * suppression requires cls_pred equality -> NMS decomposes into 8x80
//    independent per-(image,class) problems, ~27 boxes each.
//  * R1: bin valid dets into per-(b,c) buckets (global atomics).
//  * R2/R4: output sort -> rank-scatter, j-range split across 8 waves.
//  * R5: nms -> wave-register/ballot form; packed 32B records.
//  * R7: kernel-model says our 4 kernels sum to ~21us but timed graph is 75us
//    -> suspect per-dispatch overhead. Fuse ALL phases into one cooperative
//    kernel (512x512, 2 blocks/CU) with grid.sync() between phases; add
//    wave-uniform obj early-exit to the score phase (only ~20% of rows need
//    the full 85-float read + argmax).

#define NCH    85
#define NCLS   80
#define TOPK   4096
#define CAP    96     // max boxes per (image,class); mean ~27, sd ~5 -> 13 sigma
#define NBLK   512
#define NTHR   512    // 8 waves/block
#define KBLK   64     // output chunks per image (64 * 64 slots = 4096)
#define RWAVES 8      // j-split waves per rank chunk

__global__ void __launch_bounds__(NTHR, 4) fused_kernel(
        const float* __restrict__ det,
        int*   __restrict__ ibuf,   // [cells] bcnt | [B] counts | [B] person
        float* __restrict__ rec,    // cells*CAP*8 packed records
        float* __restrict__ kept,   // B*TOPK kept cls_conf
        float* __restrict__ out,
        int N, int total, int B, int cells) {
#pragma clang fp contract(off)   // box/IoU math must be bit-identical to numpy f32
    cg::grid_group grid = cg::this_grid();
    const int tid  = threadIdx.x;
    const int bid  = blockIdx.x;
    const int lane = tid & 63;
    const int wid  = tid >> 6;                 // 0..7
    const int gtid = bid * NTHR + tid;

    int* bcnt   = ibuf;
    int* counts = ibuf + cells;
    int* person = counts + B;

    __shared__ float ssc[8 * CAP];
    __shared__ int   sid[8 * CAP], perm[8 * CAP];
    __shared__ float v[TOPK];                  // 16 KB (phase C)
    __shared__ int   part[RWAVES][64];

    // ---- phase 0: zero counters -------------------------------------------
    if (gtid < cells + 2 * B) ibuf[gtid] = 0;
    grid.sync();

    // ---- phase A: score + argmax + bin (wave per row, obj early-exit) ------
    {
        const int gwave = gtid >> 6;
        const int wstep = (gridDim.x * blockDim.x) >> 6;   // 4096 waves
        for (int w = gwave; w < total; w += wstep) {
            const float* row = det + (size_t)w * NCH;
            float obj = row[4];                 // same addr all lanes
            if (obj < 0.8f) continue;           // CONF_THRES, wave-uniform

            float va = row[lane];                                  // 0..63
            float vb = (lane < NCH - 64) ? row[64 + lane] : -1.0f; // 64..84
            float bestv = -1.0f; int bestc = 1 << 30;
            if (lane >= 5) { bestv = va; bestc = lane - 5; }       // cls 0..58
            if (lane < NCH - 64) {
                int c2 = 59 + lane;                                // cls 59..79
                if (vb > bestv || (vb == bestv && c2 < bestc)) { bestv = vb; bestc = c2; }
            }
            for (int m = 32; m >= 1; m >>= 1) {
                float ov = __shfl_xor(bestv, m);
                int   oc = __shfl_xor(bestc, m);
                if (ov > bestv || (ov == bestv && oc < bestc)) { bestv = ov; bestc = oc; }
            }
            float x  = __shfl(va, 0), y  = __shfl(va, 1);
            float bw = __shfl(va, 2), bh = __shfl(va, 3);
            if (lane == 0) {
                int b = w / N, i = w - b * N;
                int cell = b * NCLS + bestc;
                int slot = atomicAdd(&bcnt[cell], 1);
                if (slot < CAP) {
                    float hw = bw * 0.5f, hh = bh * 0.5f;          // w/2 exact
                    float x1 = x - hw, y1 = y - hh, x2 = x + hw, y2 = y + hh;
                    float area = (x2 - x1 + 1.0f) * (y2 - y1 + 1.0f);
                    float4* p = (float4*)(rec + (size_t)(cell * CAP + slot) * 8);
                    p[0] = make_float4(obj * bestv, bestv, __int_as_float(i), x1);
                    p[1] = make_float4(y1, x2, y2, area);
                }
            }
        }
    }
    grid.sync();

    // ---- phase B: greedy NMS, one wave per (image,class) cell --------------
    {
        int cell = bid + NBLK * wid;            // spread cells across blocks
        int n = 0;
        if (cell < cells) { n = bcnt[cell]; if (n > CAP) n = CAP; }
        const int base = wid * CAP;
        const float* cellrec = rec + (size_t)cell * CAP * 8;

        if (n > 0) {
            for (int i = lane; i < n; i += 64) {
                float4 ra = *(const float4*)(cellrec + (size_t)i * 8);
                ssc[base + i] = ra.x;
                sid[base + i] = __float_as_int(ra.z);
            }
        }
        __syncthreads();
        if (n > 0) {
            // rank by (score desc, idx asc) == top_k order within class
            for (int i = lane; i < n; i += 64) {
                float s = ssc[base + i]; int id = sid[base + i]; int r = 0;
                for (int j = 0; j < n; j++)
                    r += (ssc[base + j] > s) || (ssc[base + j] == s && sid[base + j] < id);
                perm[base + r] = i;
            }
        }
        __syncthreads();
        if (n > 0) {
            int b = cell / NCLS, c = cell % NCLS;

            float sx1 = 0, sy1 = 0, sx2 = 0, sy2 = 0, sar = 0, scc = 0;
            if (lane < n) {
                int src = perm[base + lane];
                float4 ra = *(const float4*)(cellrec + (size_t)src * 8);
                float4 rb = *(const float4*)(cellrec + (size_t)src * 8 + 4);
                scc = ra.y; sx1 = ra.w; sy1 = rb.x; sx2 = rb.y; sy2 = rb.z; sar = rb.w;
            }
            float tx1 = 0, ty1 = 0, tx2 = 0, ty2 = 0, tar = 0, tcc = 0;
            if (n > 64 && lane + 64 < n) {
                int src = perm[base + lane + 64];
                float4 ra = *(const float4*)(cellrec + (size_t)src * 8);
                float4 rb = *(const float4*)(cellrec + (size_t)src * 8 + 4);
                tcc = ra.y; tx1 = ra.w; ty1 = rb.x; tx2 = rb.y; ty2 = rb.z; tar = rb.w;
            }

            // column masks: bit i of col(j) = (iou(i,j) > thr), i < j
            unsigned long long col0 = 0, col1a = 0, col1b = 0;
            for (int i = 0; i < n; i++) {
                float ix1, iy1, ix2, iy2, iar;
                if (i < 64) {
                    ix1 = __shfl(sx1, i); iy1 = __shfl(sy1, i);
                    ix2 = __shfl(sx2, i); iy2 = __shfl(sy2, i); iar = __shfl(sar, i);
                } else {
                    ix1 = __shfl(tx1, i - 64); iy1 = __shfl(ty1, i - 64);
                    ix2 = __shfl(tx2, i - 64); iy2 = __shfl(ty2, i - 64); iar = __shfl(tar, i - 64);
                }
                if (lane > i && lane < n) {
                    float iw = fminf(ix2, sx2) - fmaxf(ix1, sx1) + 1.0f;
                    float ih = fminf(iy2, sy2) - fmaxf(iy1, sy1) + 1.0f;
                    iw = fmaxf(iw, 0.0f); ih = fmaxf(ih, 0.0f);
                    float inter = iw * ih;
                    float iou = inter / (iar + sar - inter + 1e-16f);
                    if (iou > 0.4f) col0 |= 1ull << i;            // NMS_THRES
                }
                if (n > 64) {
                    int j2 = lane + 64;
                    if (j2 > i && j2 < n) {
                        float iw = fminf(ix2, tx2) - fmaxf(ix1, tx1) + 1.0f;
                        float ih = fminf(iy2, ty2) - fmaxf(iy1, ty1) + 1.0f;
                        iw = fmaxf(iw, 0.0f); ih = fmaxf(ih, 0.0f);
                        float inter = iw * ih;
                        float iou = inter / (iar + tar - inter + 1e-16f);
                        if (iou > 0.4f) {
                            if (i < 64) col1a |= 1ull << i;
                            else        col1b |= 1ull << (i - 64);
                        }
                    }
                }
            }

            // greedy: alive rank ii suppresses later columns with its bit set
            bool sup0 = false, sup1 = false;
            for (int ii = 0; ii < n; ii++) {
                bool alive;
                if (ii < 64) alive = !((__ballot(sup0) >> ii) & 1ull);
                else         alive = !((__ballot(sup1) >> (ii - 64)) & 1ull);
                if (alive) {
                    if (ii < 64) {
                        sup0 = sup0 | (((col0  >> ii) & 1ull) != 0);
                        sup1 = sup1 | (((col1a >> ii) & 1ull) != 0);
                    } else {
                        sup1 = sup1 | (((col1b >> (ii - 64)) & 1ull) != 0);
                    }
                }
            }

            unsigned long long alive0 = __ballot((!sup0) && (lane < n));
            int kn0 = __popcll(alive0);
            unsigned long long alive1 = 0ull;
            if (n > 64) alive1 = __ballot((!sup1) && (lane + 64 < n));
            int kn = kn0 + __popcll(alive1);                      // >= 1

            int base_o = 0;
            if (lane == 0) base_o = atomicAdd(&counts[b], kn);
            base_o = __shfl(base_o, 0);

            float* kb = kept + (size_t)b * TOPK;
            if ((!sup0) && lane < n) {
                int pos = base_o + __popcll(alive0 & ((1ull << lane) - 1ull));
                if (pos < TOPK) kb[pos] = scc;
            }
            if (n > 64 && (!sup1) && lane + 64 < n) {
                int pos = base_o + kn0 + __popcll(alive1 & ((1ull << lane) - 1ull));
                if (pos < TOPK) kb[pos] = tcc;
            }
            if (lane == 0 && c == 0) person[b] = 1;               // PERSON_ID==0
        }
    }
    grid.sync();

    // ---- phase C: per-image rank-scatter (== descending sort) --------------
    for (int cb = bid; cb < B * KBLK; cb += NBLK) {
        int b = cb / KBLK, chunk = cb % KBLK;
        int i = chunk * 64 + lane;
        int cnt = counts[b]; if (cnt > TOPK) cnt = TOPK;

        if (chunk * 64 >= cnt) {                // padding chunk (block-uniform)
            if (wid == 0) out[(size_t)b * TOPK + i] = 0.0f;
            continue;
        }
        const float* kb = kept + (size_t)b * TOPK;
        for (int j = tid; j < cnt; j += NTHR) v[j] = kb[j];
        __syncthreads();

        float val = (i < cnt) ? v[i] : 0.0f;
        int seg = (cnt + RWAVES - 1) / RWAVES;
        int j0 = wid * seg;
        int j1 = j0 + seg; if (j1 > cnt) j1 = cnt;

        int r = 0, j = j0;
        for (; j < j1 && (j & 3); j++) {
            float t = v[j]; r += (t > val) || (t == val && j < i);
        }
        for (; j + 4 <= j1; j += 4) {           // ds_read_b128 broadcast
            float4 q = *(const float4*)&v[j];
            r += (q.x > val) || (q.x == val && (j + 0) < i);
            r += (q.y > val) || (q.y == val && (j + 1) < i);
            r += (q.z > val) || (q.z == val && (j + 2) < i);
            r += (q.w > val) || (q.w == val && (j + 3) < i);
        }
        for (; j < j1; j++) {
            float t = v[j]; r += (t > val) || (t == val && j < i);
        }
        part[wid][lane] = r;
        __syncthreads();

        if (wid == 0) {
            if (i < cnt) {
                int rank = 0;
                #pragma unroll
                for (int q = 0; q < RWAVES; q++) rank += part[q][lane];
                float f = person[b] ? 1.0f : 0.0f;
                out[(size_t)b * TOPK + rank] = val * f;
            } else {
                out[(size_t)b * TOPK + i] = 0.0f;
            }
        }
        __syncthreads();                        // protect v/part reuse
    }
}

extern "C" void kernel_launch(void* const* d_in, const int* in_sizes, int n_in,
                              void* d_out, int out_size, void* d_ws, size_t ws_size,
                              hipStream_t stream) {
    const float* det = (const float*)d_in[0];
    float* out = (float*)d_out;

    int B = out_size / TOPK;                  // 8
    int N = in_sizes[0] / (B * NCH);          // 10647
    int total = B * N;
    int cells = B * NCLS;                     // 640

    // workspace layout (~2.1 MB)
    char* ws = (char*)d_ws;
    int*   ibuf = (int*)ws;                            // cells + 2B ints
    float* rec  = (float*)(ws + 4096);                 // cells*CAP*8 f32
    float* kept = rec + (size_t)cells * CAP * 8;       // B*TOPK f32

    void* args[] = { (void*)&det, (void*)&ibuf, (void*)&rec, (void*)&kept,
                     (void*)&out, (void*)&N, (void*)&total, (void*)&B, (void*)&cells };
    hipLaunchCooperativeKernel((void*)fused_kernel, dim3(NBLK), dim3(NTHR),
                               args, 0, stream);
}

// Round 9
// 136.448 us; speedup vs baseline: 1.4916x; 1.4916x over previous
//
#include <hip/hip_runtime.h>

// YOLO NMS post-processing, exact reimplementation of the JAX reference.
//  * valid = obj >= 0.8 -> ~2130 valid/image << TOPK=4096: top_k never drops
//    a valid det; invalid dets can neither suppress nor be kept.
//  * suppression requires cls_pred equality -> NMS decomposes into 8x80
//    independent per-(image,class) problems, ~27 boxes each.
//  * R5: nms in wave registers: ballot/shuffle NMS, popcount emission.
//  * R8 lesson: cooperative grid.sync costs >>kernel-boundary (XCD L2
//    coherence) -> stay multi-kernel. 1-node graph showed ~15us fixed
//    overhead; ~13us/node estimated. R9: 4 nodes -> 3. Score kernel loses
//    binning atomics (so NO init kernel needed); per-image K2 bins in LDS
//    and runs ballot-NMS; K3 full-chip rank-scatter unchanged.

#define NCH    85
#define NCLS   80
#define TOPK   4096
#define CAP    96     // max boxes per (image,class); mean ~27, sd ~5 -> 13 sigma
#define KBLK   64     // output chunks per image (64 * 64 slots = 4096)
#define RWAVES 8      // j-split waves per rank chunk

// ---- K1: per-det score/cc/cp (wave per row, obj early-exit, NO atomics) ----
__global__ void score_kernel(const float* __restrict__ det,
                             float2* __restrict__ A,   // {score or -1, cc}
                             int*    __restrict__ C,   // cp
                             int total) {
    int w    = (blockIdx.x * blockDim.x + threadIdx.x) >> 6;
    int lane = threadIdx.x & 63;
    if (w >= total) return;
    const float* row = det + (size_t)w * NCH;

    float obj = row[4];                       // same addr all lanes (broadcast)
    if (obj < 0.8f) {                         // CONF_THRES, wave-uniform
        if (lane == 0) A[w] = make_float2(-1.0f, 0.0f);
        return;
    }
    float va = row[lane];                                    // cols 0..63
    float vb = (lane < NCH - 64) ? row[64 + lane] : -1.0f;   // cols 64..84
    float bestv = -1.0f; int bestc = 1 << 30;
    if (lane >= 5) { bestv = va; bestc = lane - 5; }         // cls 0..58
    if (lane < NCH - 64) {
        int c2 = 59 + lane;                                  // cls 59..79
        if (vb > bestv || (vb == bestv && c2 < bestc)) { bestv = vb; bestc = c2; }
    }
    for (int m = 32; m >= 1; m >>= 1) {
        float ov = __shfl_xor(bestv, m);
        int   oc = __shfl_xor(bestc, m);
        if (ov > bestv || (ov == bestv && oc < bestc)) { bestv = ov; bestc = oc; }
    }
    if (lane == 0) {
        A[w] = make_float2(obj * bestv, bestv);
        C[w] = bestc;
    }
}

// ---- K2: per-image bin (LDS) + per-class ballot NMS (wave per cell) --------
__global__ void __launch_bounds__(1024) binnms_kernel(
        const float*  __restrict__ det,
        const float2* __restrict__ A,
        const int*    __restrict__ C,
        float* __restrict__ kept,
        int*   __restrict__ counts,
        int*   __restrict__ person,
        int N) {
#pragma clang fp contract(off)   // box/IoU math must be bit-identical to numpy
    int b    = blockIdx.x;
    int tid  = threadIdx.x;
    int lane = tid & 63;
    int wid  = tid >> 6;                      // 0..15

    __shared__ int   cellcnt[NCLS];
    __shared__ int   bidx[NCLS * CAP];        // 30720 B
    __shared__ int   tmpidx[16][CAP];         // per-wave rank->idx scratch
    __shared__ float v[TOPK] __attribute__((aligned(16)));   // kept cc values
    __shared__ int   kcnt, pflag;

    if (tid < NCLS) cellcnt[tid] = 0;
    if (tid == 0) { kcnt = 0; pflag = 0; }
    __syncthreads();

    const float2* Ab = A + (size_t)b * N;
    const int*    Cb = C + (size_t)b * N;

    for (int i = tid; i < N; i += 1024) {     // coalesced scan + LDS bin
        float2 t = Ab[i];
        if (t.x >= 0.0f) {
            int slot = atomicAdd(&cellcnt[Cb[i]], 1);
            if (slot < CAP) bidx[Cb[i] * CAP + slot] = i;
        }
    }
    __syncthreads();

    for (int cell = wid; cell < NCLS; cell += 16) {   // 5 cells per wave
        int n = cellcnt[cell]; if (n > CAP) n = CAP;
        if (n == 0) continue;                         // wave-uniform

        // (score, idx) per element; rank by (score desc, idx asc)
        bool a0 = lane < n, a1 = lane + 64 < n;
        int id0 = 0, id1 = 0; float s0 = 0.f, s1 = 0.f;
        if (a0) { id0 = bidx[cell * CAP + lane];      s0 = Ab[id0].x; }
        if (a1) { id1 = bidx[cell * CAP + lane + 64]; s1 = Ab[id1].x; }
        int r0 = 0, r1 = 0;
        int m0 = n < 64 ? n : 64;
        for (int j = 0; j < m0; j++) {
            float sj = __shfl(s0, j); int ij = __shfl(id0, j);
            r0 += (sj > s0) || (sj == s0 && ij < id0);
            r1 += (sj > s1) || (sj == s1 && ij < id1);
        }
        for (int j = 64; j < n; j++) {
            float sj = __shfl(s1, j - 64); int ij = __shfl(id1, j - 64);
            r0 += (sj > s0) || (sj == s0 && ij < id0);
            r1 += (sj > s1) || (sj == s1 && ij < id1);
        }
        if (a0) tmpidx[wid][r0] = id0;        // same-wave LDS, in-order
        if (a1) tmpidx[wid][r1] = id1;
        int di0 = a0 ? tmpidx[wid][lane]      : 0;
        int di1 = a1 ? tmpidx[wid][lane + 64] : 0;

        // gather sorted records: cc + corners + area (exact ref op order)
        float scc = 0, sx1 = 0, sy1 = 0, sx2 = 0, sy2 = 0, sar = 0;
        if (a0) {
            scc = Ab[di0].y;
            const float* rw = det + ((size_t)b * N + di0) * NCH;
            float x = rw[0], y = rw[1], ww = rw[2], hh2 = rw[3];
            float hw = ww * 0.5f, hh = hh2 * 0.5f;
            sx1 = x - hw; sy1 = y - hh; sx2 = x + hw; sy2 = y + hh;
            sar = (sx2 - sx1 + 1.0f) * (sy2 - sy1 + 1.0f);
        }
        float tcc = 0, tx1 = 0, ty1 = 0, tx2 = 0, ty2 = 0, tar = 0;
        if (a1) {
            tcc = Ab[di1].y;
            const float* rw = det + ((size_t)b * N + di1) * NCH;
            float x = rw[0], y = rw[1], ww = rw[2], hh2 = rw[3];
            float hw = ww * 0.5f, hh = hh2 * 0.5f;
            tx1 = x - hw; ty1 = y - hh; tx2 = x + hw; ty2 = y + hh;
            tar = (tx2 - tx1 + 1.0f) * (ty2 - ty1 + 1.0f);
        }

        // column masks: bit i of col(j) = (iou(i,j) > thr), i < j
        unsigned long long col0 = 0, col1a = 0, col1b = 0;
        for (int i = 0; i < n; i++) {
            float ix1, iy1, ix2, iy2, iar;
            if (i < 64) {
                ix1 = __shfl(sx1, i); iy1 = __shfl(sy1, i);
                ix2 = __shfl(sx2, i); iy2 = __shfl(sy2, i); iar = __shfl(sar, i);
            } else {
                ix1 = __shfl(tx1, i - 64); iy1 = __shfl(ty1, i - 64);
                ix2 = __shfl(tx2, i - 64); iy2 = __shfl(ty2, i - 64); iar = __shfl(tar, i - 64);
            }
            if (lane > i && lane < n) {
                float iw = fminf(ix2, sx2) - fmaxf(ix1, sx1) + 1.0f;
                float ih = fminf(iy2, sy2) - fmaxf(iy1, sy1) + 1.0f;
                iw = fmaxf(iw, 0.0f); ih = fmaxf(ih, 0.0f);
                float inter = iw * ih;
                float iou = inter / (iar + sar - inter + 1e-16f);
                if (iou > 0.4f) col0 |= 1ull << i;            // NMS_THRES
            }
            if (n > 64) {
                int j2 = lane + 64;
                if (j2 > i && j2 < n) {
                    float iw = fminf(ix2, tx2) - fmaxf(ix1, tx1) + 1.0f;
                    float ih = fminf(iy2, ty2) - fmaxf(iy1, ty1) + 1.0f;
                    iw = fmaxf(iw, 0.0f); ih = fmaxf(ih, 0.0f);
                    float inter = iw * ih;
                    float iou = inter / (iar + tar - inter + 1e-16f);
                    if (iou > 0.4f) {
                        if (i < 64) col1a |= 1ull << i;
                        else        col1b |= 1ull << (i - 64);
                    }
                }
            }
        }

        // greedy: alive rank ii suppresses later columns with its bit set
        bool sup0 = false, sup1 = false;
        for (int ii = 0; ii < n; ii++) {
            bool alive;
            if (ii < 64) alive = !((__ballot(sup0) >> ii) & 1ull);
            else         alive = !((__ballot(sup1) >> (ii - 64)) & 1ull);
            if (alive) {
                if (ii < 64) {
                    sup0 = sup0 | (((col0  >> ii) & 1ull) != 0);
                    sup1 = sup1 | (((col1a >> ii) & 1ull) != 0);
                } else {
                    sup1 = sup1 | (((col1b >> (ii - 64)) & 1ull) != 0);
                }
            }
        }

        // kept-emit into LDS v[] via ballot + popcount prefix
        unsigned long long alive0 = __ballot((!sup0) && a0);
        int kn0 = __popcll(alive0);
        unsigned long long alive1 = (n > 64) ? __ballot((!sup1) && a1) : 0ull;
        int kn = kn0 + __popcll(alive1);                      // >= 1

        int base_k = 0;
        if (lane == 0) base_k = atomicAdd(&kcnt, kn);
        base_k = __shfl(base_k, 0);
        if ((!sup0) && a0) {
            int pos = base_k + __popcll(alive0 & ((1ull << lane) - 1ull));
            if (pos < TOPK) v[pos] = scc;
        }
        if ((!sup1) && a1) {
            int pos = base_k + kn0 + __popcll(alive1 & ((1ull << lane) - 1ull));
            if (pos < TOPK) v[pos] = tcc;
        }
        if (lane == 0 && cell == 0) pflag = 1;                // PERSON_ID == 0
    }
    __syncthreads();

    int cnt = kcnt; if (cnt > TOPK) cnt = TOPK;
    for (int i = tid; i < cnt; i += 1024)                     // coalesced copy
        kept[(size_t)b * TOPK + i] = v[i];
    if (tid == 0) { counts[b] = cnt; person[b] = pflag; }
}

// ---- K3: per-image rank-scatter (== descending sort), 8-wave j-split -------
__global__ void rank_out_kernel(const float* __restrict__ kept,
                                const int*   __restrict__ counts,
                                const int*   __restrict__ person,
                                float* __restrict__ out) {
    int b     = blockIdx.x / KBLK;
    int chunk = blockIdx.x % KBLK;
    int tid   = threadIdx.x;                  // 0..511
    int lane  = tid & 63;
    int w     = tid >> 6;                     // 0..7
    int i     = chunk * 64 + lane;

    __shared__ float v[TOPK] __attribute__((aligned(16)));
    __shared__ int   part[RWAVES][64];

    int cnt = counts[b];
    if (cnt > TOPK) cnt = TOPK;

    if (chunk * 64 >= cnt) {                  // pure padding block
        if (w == 0) out[(size_t)b * TOPK + i] = 0.0f;
        return;
    }

    const float* kb = kept + (size_t)b * TOPK;
    for (int j = tid; j < cnt; j += 512) v[j] = kb[j];
    __syncthreads();

    float val = (i < cnt) ? v[i] : 0.0f;

    int seg = (cnt + RWAVES - 1) / RWAVES;
    int j0 = w * seg;
    int j1 = j0 + seg; if (j1 > cnt) j1 = cnt;

    int r = 0, j = j0;
    for (; j < j1 && (j & 3); j++) {
        float t = v[j]; r += (t > val) || (t == val && j < i);
    }
    for (; j + 4 <= j1; j += 4) {             // ds_read_b128 broadcast
        float4 q = *(const float4*)&v[j];
        r += (q.x > val) || (q.x == val && (j + 0) < i);
        r += (q.y > val) || (q.y == val && (j + 1) < i);
        r += (q.z > val) || (q.z == val && (j + 2) < i);
        r += (q.w > val) || (q.w == val && (j + 3) < i);
    }
    for (; j < j1; j++) {
        float t = v[j]; r += (t > val) || (t == val && j < i);
    }
    part[w][lane] = r;
    __syncthreads();

    if (w == 0) {
        if (i >= cnt) { out[(size_t)b * TOPK + i] = 0.0f; return; }
        int rank = 0;
        #pragma unroll
        for (int q = 0; q < RWAVES; q++) rank += part[q][lane];
        float f = person[b] ? 1.0f : 0.0f;
        out[(size_t)b * TOPK + rank] = val * f;
    }
}

extern "C" void kernel_launch(void* const* d_in, const int* in_sizes, int n_in,
                              void* d_out, int out_size, void* d_ws, size_t ws_size,
                              hipStream_t stream) {
    const float* det = (const float*)d_in[0];
    float* out = (float*)d_out;

    int B = out_size / TOPK;                  // 8
    int N = in_sizes[0] / (B * NCH);          // 10647
    int total = B * N;

    // workspace layout (~1.2 MB); nothing needs pre-zeroing
    char*   ws     = (char*)d_ws;
    float2* A      = (float2*)ws;                        // total float2
    int*    C      = (int*)(A + total);                  // total int
    float*  kept   = (float*)(C + total);                // B*TOPK f32
    int*    counts = (int*)(kept + (size_t)B * TOPK);    // B ints
    int*    person = counts + B;                         // B ints

    int gridA = (total + 3) / 4;                         // 4 waves / block
    score_kernel<<<gridA, 256, 0, stream>>>(det, A, C, total);
    binnms_kernel<<<B, 1024, 0, stream>>>(det, A, C, kept, counts, person, N);
    rank_out_kernel<<<B * KBLK, 512, 0, stream>>>(kept, counts, person, out);
}

// Round 10
// 62.313 us; speedup vs baseline: 3.2662x; 2.1897x over previous
//
#include <hip/hip_runtime.h>

// YOLO NMS post-processing, exact reimplementation of the JAX reference.
//  * valid = obj >= 0.8 -> ~2130 valid/image << TOPK=4096: top_k never drops
//    a valid det; invalid dets can neither suppress nor be kept.
//  * suppression requires cls_pred equality -> NMS decomposes into 8x80
//    independent per-(image,class) problems, ~27 boxes each (CAP=96 ~13sig).
//  * R9 lesson: __shfl==ds_bpermute; per-CU LDS-pipe contention killed the
//    8-block version. R10: NO global atomics anywhere (no init node, 3 nodes),
//    per-cell membership via byte-class scan + ballot-compact (order-free:
//    rank re-sorts), all uniform-index shuffles -> v_readlane (VALU pipe).

#define NCH    85
#define NCLS   80
#define TOPK   4096
#define CAP    96
#define KBLK   64     // output chunks per image (64 * 64 slots = 4096)
#define RWAVES 8      // j-split waves per rank chunk

__device__ __forceinline__ float rlf(float v, int l) {
    return __uint_as_float(__builtin_amdgcn_readlane(__float_as_uint(v), l));
}
__device__ __forceinline__ int rli(int v, int l) {
    return __builtin_amdgcn_readlane(v, l);
}

// ---- K1: per-det score/cc (float2), class byte, corner float4 --------------
__global__ void score_kernel(const float* __restrict__ det,
                             float2* __restrict__ A,
                             unsigned char* __restrict__ Cc,
                             float4* __restrict__ REC,
                             int N, int NP, int total) {
#pragma clang fp contract(off)   // corner math must match numpy f32 exactly
    int w    = (blockIdx.x * blockDim.x + threadIdx.x) >> 6;
    int lane = threadIdx.x & 63;
    if (w >= total) return;
    const float* row = det + (size_t)w * NCH;
    int b = w / N, i = w - b * N;

    float obj = row[4];                       // broadcast load
    if (obj < 0.8f) {                         // CONF_THRES, wave-uniform
        if (lane == 0) Cc[(size_t)b * NP + i] = 0xFFu;
        return;
    }
    float va = row[lane];                                    // cols 0..63
    float vb = (lane < NCH - 64) ? row[64 + lane] : -1.0f;   // cols 64..84
    float bestv = -1.0f; int bestc = 1 << 30;
    if (lane >= 5) { bestv = va; bestc = lane - 5; }         // cls 0..58
    if (lane < NCH - 64) {
        int c2 = 59 + lane;                                  // cls 59..79
        if (vb > bestv || (vb == bestv && c2 < bestc)) { bestv = vb; bestc = c2; }
    }
    for (int m = 32; m >= 1; m >>= 1) {
        float ov = __shfl_xor(bestv, m);
        int   oc = __shfl_xor(bestc, m);
        if (ov > bestv || (ov == bestv && oc < bestc)) { bestv = ov; bestc = oc; }
    }
    float x  = rlf(va, 0), y  = rlf(va, 1);
    float bw = rlf(va, 2), bh = rlf(va, 3);
    if (lane == 0) {
        float hw = bw * 0.5f, hh = bh * 0.5f;                // w/2 exact
        A[(size_t)b * NP + i]  = make_float2(obj * bestv, bestv);
        Cc[(size_t)b * NP + i] = (unsigned char)bestc;
        REC[(size_t)w] = make_float4(x - hw, y - hh, x + hw, y + hh);
    }
}

// ---- K2: one wave per (image,class): scan bytes, rank, IoU, greedy ---------
__global__ void __launch_bounds__(64) nms_kernel(
        const float2* __restrict__ A,
        const unsigned char* __restrict__ Cc,
        const float4* __restrict__ REC,
        float* __restrict__ kv,
        int*   __restrict__ kcnt,
        int N, int NT, int NP) {
#pragma clang fp contract(off)   // IoU math must be bit-identical to numpy f32
    int cell = blockIdx.x;
    int b = cell / NCLS, c = cell % NCLS;
    int lane = threadIdx.x;
    unsigned long long mlt = (1ull << lane) - 1ull;

    __shared__ int lidx[CAP];
    __shared__ int tmpidx[CAP];

    // --- membership scan over byte classes (order-free append) ---
    const unsigned char* Cb = Cc + (size_t)b * NP;
    int cnt = 0;
    uint4 q = *(const uint4*)(Cb + lane * 16);          // prefetch t=0
    for (int t = 0; t < NT; t++) {
        uint4 qn;
        if (t + 1 < NT) qn = *(const uint4*)(Cb + (size_t)(t + 1) * 1024 + lane * 16);
        int i0 = t * 1024 + lane * 16;
        unsigned xs[4] = { q.x, q.y, q.z, q.w };
        unsigned mm = 0;
        #pragma unroll
        for (int kk = 0; kk < 16; kk++) {
            unsigned byte = (xs[kk >> 2] >> ((kk & 3) * 8)) & 0xFFu;
            if (byte == (unsigned)c && (i0 + kk) < N) mm |= 1u << kk;
        }
        if (__ballot(mm != 0)) {
            #pragma unroll
            for (int kk = 0; kk < 16; kk++) {
                unsigned long long mk = __ballot((mm >> kk) & 1u);
                if (mk) {
                    if ((mm >> kk) & 1u) {
                        int p = cnt + __popcll(mk & mlt);
                        if (p < CAP) lidx[p] = i0 + kk;
                    }
                    cnt += __popcll(mk);
                }
            }
        }
        q = qn;
    }
    int n = cnt < CAP ? cnt : CAP;
    if (n == 0) { if (lane == 0) kcnt[cell] = 0; return; }

    bool a0 = lane < n, a1 = lane + 64 < n;
    const float2* Ab = A + (size_t)b * NP;
    int id0 = a0 ? lidx[lane]      : 0;
    int id1 = a1 ? lidx[lane + 64] : 0;
    float s0 = a0 ? Ab[id0].x : 0.0f;
    float s1 = a1 ? Ab[id1].x : 0.0f;

    // --- rank by (score desc, idx asc) == top_k order within class ---
    int r0 = 0, r1 = 0;
    int m0 = n < 64 ? n : 64;
    for (int j = 0; j < m0; j++) {
        float sj = rlf(s0, j); int ij = rli(id0, j);
        r0 += (sj > s0) || (sj == s0 && ij < id0);
        r1 += (sj > s1) || (sj == s1 && ij < id1);
    }
    for (int j = 64; j < n; j++) {
        float sj = rlf(s1, j - 64); int ij = rli(id1, j - 64);
        r0 += (sj > s0) || (sj == s0 && ij < id0);
        r1 += (sj > s1) || (sj == s1 && ij < id1);
    }
    if (a0) tmpidx[r0] = id0;      // same-wave LDS, program-order safe
    if (a1) tmpidx[r1] = id1;
    int di0 = a0 ? tmpidx[lane]      : 0;
    int di1 = a1 ? tmpidx[lane + 64] : 0;

    // --- gather sorted records: cc + corners + area (exact ref op order) ---
    float scc = 0, x10 = 0, y10 = 0, x20 = 0, y20 = 0, ar0 = 0;
    if (a0) {
        scc = Ab[di0].y;
        float4 rc = REC[(size_t)b * N + di0];
        x10 = rc.x; y10 = rc.y; x20 = rc.z; y20 = rc.w;
        ar0 = (x20 - x10 + 1.0f) * (y20 - y10 + 1.0f);
    }
    float tcc = 0, x11 = 0, y11 = 0, x21 = 0, y21 = 0, ar1 = 0;
    if (a1) {
        tcc = Ab[di1].y;
        float4 rc = REC[(size_t)b * N + di1];
        x11 = rc.x; y11 = rc.y; x21 = rc.z; y21 = rc.w;
        ar1 = (x21 - x11 + 1.0f) * (y21 - y11 + 1.0f);
    }

    // --- column masks: bit i of col(j) = (iou(i,j) > thr), i < j ---
    unsigned long long col0 = 0, col1a = 0, col1b = 0;
    for (int i = 0; i < n; i++) {
        float ix1, iy1, ix2, iy2, iar;
        if (i < 64) {
            ix1 = rlf(x10, i); iy1 = rlf(y10, i);
            ix2 = rlf(x20, i); iy2 = rlf(y20, i); iar = rlf(ar0, i);
        } else {
            ix1 = rlf(x11, i - 64); iy1 = rlf(y11, i - 64);
            ix2 = rlf(x21, i - 64); iy2 = rlf(y21, i - 64); iar = rlf(ar1, i - 64);
        }
        if (lane > i && lane < n) {
            float iw = fminf(ix2, x20) - fmaxf(ix1, x10) + 1.0f;
            float ih = fminf(iy2, y20) - fmaxf(iy1, y10) + 1.0f;
            iw = fmaxf(iw, 0.0f); ih = fmaxf(ih, 0.0f);
            float inter = iw * ih;
            float iou = inter / (iar + ar0 - inter + 1e-16f);
            if (iou > 0.4f) col0 |= 1ull << i;                // NMS_THRES
        }
        if (n > 64) {
            int j2 = lane + 64;
            if (j2 > i && j2 < n) {
                float iw = fminf(ix2, x21) - fmaxf(ix1, x11) + 1.0f;
                float ih = fminf(iy2, y21) - fmaxf(iy1, y11) + 1.0f;
                iw = fmaxf(iw, 0.0f); ih = fmaxf(ih, 0.0f);
                float inter = iw * ih;
                float iou = inter / (iar + ar1 - inter + 1e-16f);
                if (iou > 0.4f) {
                    if (i < 64) col1a |= 1ull << i;
                    else        col1b |= 1ull << (i - 64);
                }
            }
        }
    }

    // --- greedy: alive rank ii suppresses later columns with its bit set ---
    bool sup0 = false, sup1 = false;
    for (int ii = 0; ii < n; ii++) {
        bool alive;
        if (ii < 64) alive = !((__ballot(sup0) >> ii) & 1ull);
        else         alive = !((__ballot(sup1) >> (ii - 64)) & 1ull);
        if (alive) {
            if (ii < 64) {
                sup0 = sup0 | (((col0  >> ii) & 1ull) != 0);
                sup1 = sup1 | (((col1a >> ii) & 1ull) != 0);
            } else {
                sup1 = sup1 | (((col1b >> (ii - 64)) & 1ull) != 0);
            }
        }
    }

    // --- emit kept cc (sorted order) into this cell's private segment ---
    unsigned long long alive0 = __ballot((!sup0) && a0);
    int kn0 = __popcll(alive0);
    unsigned long long alive1 = (n > 64) ? __ballot((!sup1) && a1) : 0ull;
    int kn = kn0 + __popcll(alive1);
    float* kvc = kv + (size_t)cell * CAP;
    if ((!sup0) && a0) kvc[__popcll(alive0 & mlt)] = scc;
    if ((!sup1) && a1) kvc[kn0 + __popcll(alive1 & mlt)] = tcc;
    if (lane == 0) kcnt[cell] = kn;
}

// ---- K3: prefix-scan 80 cell counts, compact, rank-scatter ------------------
__global__ void __launch_bounds__(512) rank_out_kernel(
        const float* __restrict__ kv,
        const int*   __restrict__ kcnt,
        float* __restrict__ out) {
    int b     = blockIdx.x / KBLK;
    int chunk = blockIdx.x % KBLK;
    int tid   = threadIdx.x;                  // 0..511
    int lane  = tid & 63;
    int wid   = tid >> 6;                     // 0..7
    int i     = chunk * 64 + lane;

    __shared__ int   off[NCLS];
    __shared__ float v[TOPK] __attribute__((aligned(16)));
    __shared__ int   part[RWAVES][64];

    if (tid < NCLS) off[tid] = kcnt[b * NCLS + tid];
    __syncthreads();
    #pragma unroll
    for (int s = 1; s < NCLS; s <<= 1) {      // Hillis-Steele inclusive scan
        int x = 0;
        if (tid < NCLS && tid >= s) x = off[tid - s];
        __syncthreads();
        if (tid < NCLS) off[tid] += x;
        __syncthreads();
    }
    int cnt = off[NCLS - 1];
    if (cnt > TOPK) cnt = TOPK;
    float f = (off[0] > 0) ? 1.0f : 0.0f;     // person: class-0 kept count > 0

    if (chunk * 64 >= cnt) {                  // pure padding chunk
        if (wid == 0) out[(size_t)b * TOPK + i] = 0.0f;
        return;
    }

    // compaction: wave wid copies cells wid, wid+8, ...
    for (int cell = wid; cell < NCLS; cell += RWAVES) {
        int e1 = off[cell];
        int e0 = (cell == 0) ? 0 : off[cell - 1];
        int kc = e1 - e0;
        const float* src = kv + (size_t)(b * NCLS + cell) * CAP;
        for (int j = lane; j < kc; j += 64)
            if (e0 + j < TOPK) v[e0 + j] = src[j];
    }
    __syncthreads();

    float val = (i < cnt) ? v[i] : 0.0f;
    int seg = (cnt + RWAVES - 1) / RWAVES;
    int j0 = wid * seg;
    int j1 = j0 + seg; if (j1 > cnt) j1 = cnt;

    int r = 0, j = j0;
    for (; j < j1 && (j & 3); j++) {
        float t = v[j]; r += (t > val) || (t == val && j < i);
    }
    for (; j + 4 <= j1; j += 4) {             // ds_read_b128 broadcast
        float4 q = *(const float4*)&v[j];
        r += (q.x > val) || (q.x == val && (j + 0) < i);
        r += (q.y > val) || (q.y == val && (j + 1) < i);
        r += (q.z > val) || (q.z == val && (j + 2) < i);
        r += (q.w > val) || (q.w == val && (j + 3) < i);
    }
    for (; j < j1; j++) {
        float t = v[j]; r += (t > val) || (t == val && j < i);
    }
    part[wid][lane] = r;
    __syncthreads();

    if (wid == 0) {
        if (i < cnt) {
            int rank = 0;
            #pragma unroll
            for (int qq = 0; qq < RWAVES; qq++) rank += part[qq][lane];
            out[(size_t)b * TOPK + rank] = val * f;
        } else {
            out[(size_t)b * TOPK + i] = 0.0f;
        }
    }
}

extern "C" void kernel_launch(void* const* d_in, const int* in_sizes, int n_in,
                              void* d_out, int out_size, void* d_ws, size_t ws_size,
                              hipStream_t stream) {
    const float* det = (const float*)d_in[0];
    float* out = (float*)d_out;

    int B = out_size / TOPK;                  // 8
    int N = in_sizes[0] / (B * NCH);          // 10647
    int total = B * N;
    int NT = (N + 1023) / 1024;               // 11
    int NP = NT * 1024;                       // 11264

    // workspace layout (~2.4 MB), 256B-aligned regions, nothing pre-zeroed
    char* p = (char*)d_ws;
    auto align256 = [](size_t x) { return (x + 255) & ~(size_t)255; };
    size_t o = 0;
    unsigned char* Cc = (unsigned char*)(p + o); o = align256(o + (size_t)B * NP);
    float2* A   = (float2*)(p + o);              o = align256(o + (size_t)B * NP * sizeof(float2));
    float4* REC = (float4*)(p + o);              o = align256(o + (size_t)total * sizeof(float4));
    float*  kv  = (float*)(p + o);               o = align256(o + (size_t)B * NCLS * CAP * sizeof(float));
    int*   kcnt = (int*)(p + o);

    int gridA = (total + 3) / 4;              // 4 waves / 256-thr block
    score_kernel<<<gridA, 256, 0, stream>>>(det, A, Cc, REC, N, NP, total);
    nms_kernel<<<B * NCLS, 64, 0, stream>>>(A, Cc, REC, kv, kcnt, N, NT, NP);
    rank_out_kernel<<<B * KBLK, 512, 0, stream>>>(kv, kcnt, out);
}